// Round 6
// baseline (127.318 us; speedup 1.0000x reference)
//
#include <hip/hip_runtime.h>
#include <hip/hip_bf16.h>

#define NROW 8192   // B*A = 64*128
#define INC  128
#define OUTC 64
#define BG   16     // key-split factor

// Q is pre-scaled by log2(e)/sqrt(64) at projection time, so attention
// computes p = exp2(q'.k) with a single v_exp_f32 per score.
#define QSCALE 0.18033688011112042f

typedef __bf16 bf16x8 __attribute__((ext_vector_type(8)));
typedef __bf16 bf16x4 __attribute__((ext_vector_type(4)));
typedef short  s16x4  __attribute__((ext_vector_type(4)));
typedef float  f32x4  __attribute__((ext_vector_type(4)));

static __device__ __forceinline__ f32x4 mfma16(bf16x8 a, bf16x8 b, f32x4 c) {
    return __builtin_amdgcn_mfma_f32_16x16x32_bf16(a, b, c, 0, 0, 0);
}
// 16x16x16 bf16 (K=16). C/D of S^T IS the A-operand layout of P for PV.
static __device__ __forceinline__ f32x4 mfma1k(s16x4 a, s16x4 b, f32x4 c) {
    return __builtin_amdgcn_mfma_f32_16x16x16bf16_1k(a, b, c, 0, 0, 0);
}

static __device__ __forceinline__ bf16x8 cvt8(float4 lo, float4 hi) {
    bf16x8 r;
    r[0] = (__bf16)lo.x; r[1] = (__bf16)lo.y; r[2] = (__bf16)lo.z; r[3] = (__bf16)lo.w;
    r[4] = (__bf16)hi.x; r[5] = (__bf16)hi.y; r[6] = (__bf16)hi.z; r[7] = (__bf16)hi.w;
    return r;
}

// ---------------------------------------------------------------------------
// Kernel 1: projection via MFMA. grid = 768 = mat(3) x b(64) x aq(4).
// Q/K/V written in FRAGMENT-TILED layout (512-B 16x16 tiles), Q pre-scaled.
__global__ __launch_bounds__(256) void proj_kernel(
    const float* __restrict__ feat,
    const float* __restrict__ Wq, const float* __restrict__ bq,
    const float* __restrict__ Wk, const float* __restrict__ bk,
    const float* __restrict__ Wv, const float* __restrict__ bv,
    __hip_bfloat16* __restrict__ qbf, __hip_bfloat16* __restrict__ kbf,
    __hip_bfloat16* __restrict__ vbf, __hip_bfloat16* __restrict__ vnb)
{
    __shared__ float slab[32 * 132];
    __shared__ float vbuf[32 * 66];
    __shared__ float invb[32];

    const int blk = blockIdx.x;
    const int mat = blk >> 8;
    const int b   = (blk >> 2) & 63;
    const int a0  = (blk & 3) * 32;
    const int r0  = b * 128 + a0;
    const float* fb = feat + (size_t)b * INC * 128;

    for (int i = threadIdx.x; i < 32 * 128; i += 256) {
        int c = i >> 5, a = i & 31;
        slab[a * 132 + c] = fb[c * 128 + a0 + a];
    }
    __syncthreads();

    const int w    = threadIdx.x >> 6;
    const int lane = threadIdx.x & 63;
    const int l16  = lane & 15;
    const int quad = lane >> 4;
    const int n0   = w * 16;

    const float* W    = (mat == 0) ? Wq : (mat == 1) ? Wk : Wv;
    const float* bias = (mat == 0) ? bq : (mat == 1) ? bk : bv;

    f32x4 acc[2] = {{0.f,0.f,0.f,0.f},{0.f,0.f,0.f,0.f}};
    #pragma unroll
    for (int kc = 0; kc < 4; ++kc) {
        const int k0 = kc * 32 + quad * 8;
        const float* wr = W + (n0 + l16) * INC + k0;
        bf16x8 bfr = cvt8(*(const float4*)wr, *(const float4*)(wr + 4));
        #pragma unroll
        for (int u = 0; u < 2; ++u) {
            const float* ar = slab + (u * 16 + l16) * 132 + k0;
            bf16x8 afr = cvt8(*(const float4*)ar, *(const float4*)(ar + 4));
            acc[u] = mfma16(afr, bfr, acc[u]);
        }
    }
    const float bl = bias[n0 + l16];
    const float sc = (mat == 0) ? QSCALE : 1.0f;

    if (mat < 2) {
        __hip_bfloat16* dst = mat ? kbf : qbf;
        #pragma unroll
        for (int u = 0; u < 2; ++u) {
            const int base = ((((r0 >> 4) + u) * 4 + w) << 8) + l16;
            #pragma unroll
            for (int r = 0; r < 4; ++r)
                dst[base + (quad * 4 + r) * 16] = __float2bfloat16((acc[u][r] + bl) * sc);
        }
    } else {
        #pragma unroll
        for (int u = 0; u < 2; ++u)
            #pragma unroll
            for (int r = 0; r < 4; ++r)
                vbuf[(u * 16 + quad * 4 + r) * 66 + n0 + l16] = acc[u][r] + bl;
        __syncthreads();
        const int rl = threadIdx.x >> 3;
        const int jj = threadIdx.x & 7;
        float ss = 0.f;
        #pragma unroll
        for (int i = 0; i < 8; ++i) {
            float x = vbuf[rl * 66 + jj * 8 + i];
            ss += x * x;
        }
        ss += __shfl_xor(ss, 1, 64);
        ss += __shfl_xor(ss, 2, 64);
        ss += __shfl_xor(ss, 4, 64);
        if (jj == 0) invb[rl] = rsqrtf(fmaxf(ss, 1e-24f));
        __syncthreads();
        float inv = invb[rl];
        bf16x8 vp;
        #pragma unroll
        for (int i = 0; i < 8; ++i)
            vp[i] = (__bf16)(vbuf[rl * 66 + jj * 8 + i] * inv);
        *(bf16x8*)(vnb + (size_t)(r0 + rl) * 64 + jj * 8) = vp;
        const int tl = threadIdx.x & 15;
        const int n  = (threadIdx.x >> 4) & 3;
        const int s_ = threadIdx.x >> 6;
        bf16x8 pack;
        #pragma unroll
        for (int j = 0; j < 8; ++j) {
            int key = s_ * 8 + j;
            pack[j] = (__bf16)(vbuf[key * 66 + n * 16 + tl] * invb[key]);
        }
        const int base = ((((r0 >> 4) + (s_ >> 1)) * 4 + n) << 8) + tl * 16 + (s_ & 1) * 8;
        *(bf16x8*)(vbf + base) = pack;
    }
}

// ---------------------------------------------------------------------------
// Kernel 2: attention. grid = 256 = qb(16) x bg(16); block = 512 q-rows x
// 512 keys; EXACTLY 1 block/CU, zero tail.
//
// ROUND 6: round 5 confirmed the per-CU VMEM-issue model (halving VMEM
// instrs dropped attn 55 -> <46us). Apply again: 128 q-rows per wave
// (of[8][4] = 128 accum regs) -> per-CU VMEM instrs halve 393k -> 196k;
// each K/V load feeds 24 MFMAs. Unified reg estimate: of 128 + qf 64 +
// Kdbuf 32 + Vdbuf 32 + temps ~30 = ~290 < 512 cap at (256,1). 1 wave/SIMD:
// latency hidden by 8-way independent u-subtiles + 1-iter prefetch
// distance (~500 cyc of work per iter).
#define ATTN_ITER(K00,K01,K10,K11, NK00,NK01,NK10,NK11,                      \
                  V0,V1,V2,V3,V4,V5,V6,V7,                                   \
                  NV0,NV1,NV2,NV3,NV4,NV5,NV6,NV7)                           \
    do {                                                                     \
        NV0 = *(const s16x4*)(vp);                                           \
        NV1 = *(const s16x4*)(vp + 512);                                     \
        NV2 = *(const s16x4*)(vp + 1024);                                    \
        NV3 = *(const s16x4*)(vp + 1536);                                    \
        NV4 = *(const s16x4*)(vp + 2048);                                    \
        NV5 = *(const s16x4*)(vp + 2560);                                    \
        NV6 = *(const s16x4*)(vp + 3072);                                    \
        NV7 = *(const s16x4*)(vp + 3584);                                    \
        NK00 = *(const bf16x8*)(kp);                                         \
        NK01 = *(const bf16x8*)(kp + 1024);                                  \
        NK10 = *(const bf16x8*)(kp + 2048);                                  \
        NK11 = *(const bf16x8*)(kp + 3072);                                  \
        vp += 4096; kp += 4096;                                              \
        const f32x4 zero = (f32x4){0.f, 0.f, 0.f, 0.f};                      \
        _Pragma("unroll")                                                    \
        for (int u = 0; u < 8; ++u) {                                        \
            f32x4 s0 = mfma16(K00, qf32[u][0], zero);                        \
            s0       = mfma16(K01, qf32[u][1], s0);                          \
            f32x4 s1 = mfma16(K10, qf32[u][0], zero);                        \
            s1       = mfma16(K11, qf32[u][1], s1);                          \
            union { bf16x4 v; s16x4 s; } pf0, pf1;                           \
            _Pragma("unroll")                                                \
            for (int r = 0; r < 4; ++r) {                                    \
                float p0 = __builtin_amdgcn_exp2f(s0[r]);                    \
                float p1 = __builtin_amdgcn_exp2f(s1[r]);                    \
                lp[u] += p0 + p1;                                            \
                pf0.v[r] = (__bf16)p0;                                       \
                pf1.v[r] = (__bf16)p1;                                       \
            }                                                                \
            of[u][0] = mfma1k(pf0.s, V0, of[u][0]);                          \
            of[u][0] = mfma1k(pf1.s, V4, of[u][0]);                          \
            of[u][1] = mfma1k(pf0.s, V1, of[u][1]);                          \
            of[u][1] = mfma1k(pf1.s, V5, of[u][1]);                          \
            of[u][2] = mfma1k(pf0.s, V2, of[u][2]);                          \
            of[u][2] = mfma1k(pf1.s, V6, of[u][2]);                          \
            of[u][3] = mfma1k(pf0.s, V3, of[u][3]);                          \
            of[u][3] = mfma1k(pf1.s, V7, of[u][3]);                          \
        }                                                                    \
    } while (0)

__global__ __launch_bounds__(256, 1) void attn_kernel(
    const __hip_bfloat16* __restrict__ qbf,
    const __hip_bfloat16* __restrict__ kbf,
    const __hip_bfloat16* __restrict__ vbf,
    float* __restrict__ Opart, float* __restrict__ lpart)
{
    const int qb    = blockIdx.x >> 4;
    const int bg    = blockIdx.x & 15;
    const int w     = threadIdx.x >> 6;
    const int lane  = threadIdx.x & 63;
    const int l16   = lane & 15;
    const int quad  = lane >> 4;
    const int r0    = qb * 512 + w * 128;             // 128 q-rows per wave
    const int fo    = l16 * 16 + quad * 4;            // K=16 frag elem offset
    const int fo32  = l16 * 16 + (quad & 1) * 8;      // K=32 frag elem offset
    const int qh    = quad >> 1;                      // K=32 tile-pair half

    // Q fragments in K=32 form: 8 x 16-row subtiles
    bf16x8 qf32[8][2];
    #pragma unroll
    for (int u = 0; u < 8; ++u)
        #pragma unroll
        for (int p = 0; p < 2; ++p)
            qf32[u][p] = *(const bf16x8*)(qbf +
                ((((r0 >> 4) + u) * 4 + p * 2 + qh) << 8) + fo32);

    f32x4 of[8][4];
    float lp[8] = {0.f, 0.f, 0.f, 0.f, 0.f, 0.f, 0.f, 0.f};
    #pragma unroll
    for (int u = 0; u < 8; ++u)
        #pragma unroll
        for (int n = 0; n < 4; ++n)
            of[u][n] = (f32x4){0.f, 0.f, 0.f, 0.f};

    // byte pointers: chunk stride 2048 B, iteration (2 chunks) stride 4096 B
    const int ck0 = bg * 32;                          // 32 chunks = 512 keys
    const char* kp = (const char*)kbf + ck0 * 2048 + qh * 512 + fo32 * 2;
    const char* vp = (const char*)vbf + ck0 * 2048 + fo * 2;

    bf16x8 kA00, kA01, kA10, kA11, kB00, kB01, kB10, kB11;
    s16x4  vA0, vA1, vA2, vA3, vA4, vA5, vA6, vA7;
    s16x4  vB0, vB1, vB2, vB3, vB4, vB5, vB6, vB7;

    // prologue: load iteration 0's K and V
    vA0 = *(const s16x4*)(vp);
    vA1 = *(const s16x4*)(vp + 512);
    vA2 = *(const s16x4*)(vp + 1024);
    vA3 = *(const s16x4*)(vp + 1536);
    vA4 = *(const s16x4*)(vp + 2048);
    vA5 = *(const s16x4*)(vp + 2560);
    vA6 = *(const s16x4*)(vp + 3072);
    vA7 = *(const s16x4*)(vp + 3584);
    kA00 = *(const bf16x8*)(kp);
    kA01 = *(const bf16x8*)(kp + 1024);
    kA10 = *(const bf16x8*)(kp + 2048);
    kA11 = *(const bf16x8*)(kp + 3072);
    vp += 4096; kp += 4096;

    #pragma unroll 1
    for (int body = 0; body < 8; ++body) {
        ATTN_ITER(kA00, kA01, kA10, kA11, kB00, kB01, kB10, kB11,
                  vA0, vA1, vA2, vA3, vA4, vA5, vA6, vA7,
                  vB0, vB1, vB2, vB3, vB4, vB5, vB6, vB7);
        ATTN_ITER(kB00, kB01, kB10, kB11, kA00, kA01, kA10, kA11,
                  vB0, vB1, vB2, vB3, vB4, vB5, vB6, vB7,
                  vA0, vA1, vA2, vA3, vA4, vA5, vA6, vA7);
    }

    // per-wave l reduction across quads
    #pragma unroll
    for (int u = 0; u < 8; ++u) {
        float v = lp[u];
        v += __shfl_xor(v, 16, 64);
        v += __shfl_xor(v, 32, 64);
        lp[u] = v;
    }

    // streaming per-wave partial: tile = qb*4 + w owns rows [r0, r0+128)
    const int task = (qb * 4 + w) * 16 + bg;
    float* Ob = Opart + (size_t)task * 8192;
    #pragma unroll
    for (int u = 0; u < 8; ++u)
        #pragma unroll
        for (int n = 0; n < 4; ++n)
            #pragma unroll
            for (int r = 0; r < 4; ++r)
                Ob[(u * 16 + quad * 4 + r) * 64 + n * 16 + l16] = of[u][n][r];
    if (quad == 0) {
        #pragma unroll
        for (int u = 0; u < 8; ++u)
            lpart[task * 128 + u * 16 + l16] = lp[u];
    }
}

// ---------------------------------------------------------------------------
// Kernel 3: combine 16 partials/tile (128-row tiles), divide by l,
// l2-normalize -> qnb (bf16). grid = 2048 x 256 (full device).
__global__ __launch_bounds__(256) void combine_kernel(
    const float* __restrict__ Opart, const float* __restrict__ lpart,
    __hip_bfloat16* __restrict__ qnb)
{
    const int r    = blockIdx.x * 4 + (threadIdx.x >> 6);
    const int c    = threadIdx.x & 63;
    const int tile = r >> 7, row = r & 127;
    float acc = 0.f, lsum = 0.f;
    #pragma unroll
    for (int g = 0; g < 16; ++g) {
        int task = tile * 16 + g;
        acc  += Opart[(size_t)task * 8192 + row * 64 + c];
        lsum += lpart[task * 128 + row];
    }
    float q = acc / lsum;
    float ss = q * q;
    ss += __shfl_xor(ss, 1, 64);
    ss += __shfl_xor(ss, 2, 64);
    ss += __shfl_xor(ss, 4, 64);
    ss += __shfl_xor(ss, 8, 64);
    ss += __shfl_xor(ss, 16, 64);
    ss += __shfl_xor(ss, 32, 64);
    qnb[(size_t)r * 64 + c] = __float2bfloat16(q * rsqrtf(fmaxf(ss, 1e-24f)));
}

// ---------------------------------------------------------------------------
// Kernel 4: sim = (1/128) * Vn(64x8192) @ Qn(64x8192)^T, split-K MFMA GEMM.
// 256-thread blocks: 4 waves each take 2 of the 8 k-slices of this block's
// 256-key range; atomicAdd partials (4K distinct addresses).
__global__ __launch_bounds__(256) void sim_kernel(
    const __hip_bfloat16* __restrict__ vnb,
    const __hip_bfloat16* __restrict__ qnb,
    float* __restrict__ out)
{
    const int w    = threadIdx.x >> 6;
    const int lane = threadIdx.x & 63;
    const int l16  = lane & 15;
    const int quad = lane >> 4;
    const int kblk = blockIdx.x * 256;

    f32x4 acc[4][4];
    #pragma unroll
    for (int mi = 0; mi < 4; ++mi)
        #pragma unroll
        for (int ni = 0; ni < 4; ++ni)
            acc[mi][ni] = (f32x4){0.f, 0.f, 0.f, 0.f};

    #pragma unroll
    for (int s = 0; s < 2; ++s) {
        const int ks = w * 2 + s;
        const int k0 = kblk + ks * 32 + quad * 8;
        bf16x8 af[4], bfv[4];
        #pragma unroll
        for (int mi = 0; mi < 4; ++mi)
            af[mi] = *(const bf16x8*)(vnb + (size_t)(mi * 16 + l16) * 8192 + k0);
        #pragma unroll
        for (int ni = 0; ni < 4; ++ni)
            bfv[ni] = *(const bf16x8*)(qnb + (size_t)(ni * 16 + l16) * 8192 + k0);
        #pragma unroll
        for (int mi = 0; mi < 4; ++mi)
            #pragma unroll
            for (int ni = 0; ni < 4; ++ni)
                acc[mi][ni] = mfma16(af[mi], bfv[ni], acc[mi][ni]);
    }

    #pragma unroll
    for (int mi = 0; mi < 4; ++mi)
        #pragma unroll
        for (int ni = 0; ni < 4; ++ni)
            #pragma unroll
            for (int r = 0; r < 4; ++r)
                atomicAdd(&out[(mi * 16 + quad * 4 + r) * 64 + ni * 16 + l16],
                          acc[mi][ni][r] * (1.f / 128.f));
}

// ---------------------------------------------------------------------------
extern "C" void kernel_launch(void* const* d_in, const int* in_sizes, int n_in,
                              void* d_out, int out_size, void* d_ws, size_t ws_size,
                              hipStream_t stream)
{
    const float* feat = (const float*)d_in[0];
    const float* Wq   = (const float*)d_in[1];
    const float* bq   = (const float*)d_in[2];
    const float* Wk   = (const float*)d_in[3];
    const float* bk   = (const float*)d_in[4];
    const float* Wv   = (const float*)d_in[5];
    const float* bv   = (const float*)d_in[6];
    float* out = (float*)d_out;

    const size_t MB = 1u << 20;
    char* ws = (char*)d_ws;
    __hip_bfloat16* qbf = (__hip_bfloat16*)(ws);              // 1 MB (frag-tiled, pre-scaled)
    __hip_bfloat16* kbf = (__hip_bfloat16*)(ws + 1 * MB);     // 1 MB (frag-tiled)
    __hip_bfloat16* vbf = (__hip_bfloat16*)(ws + 2 * MB);     // 1 MB (frag-tiled)
    __hip_bfloat16* vnb = (__hip_bfloat16*)(ws + 3 * MB);     // 1 MB (row-major)
    float* Opart = (float*)(ws + 4 * MB);                     // 32 MB (1024 x 32 KB)
    float* lpart = (float*)(ws + 36 * MB);                    // 512 KB
    __hip_bfloat16* qnb = (__hip_bfloat16*)(ws + 37 * MB);    // 1 MB

    (void)hipMemsetAsync(out, 0, 64 * 64 * sizeof(float), stream);
    proj_kernel<<<768, 256, 0, stream>>>(feat, Wq, bq, Wk, bk, Wv, bv, qbf, kbf, vbf, vnb);
    attn_kernel<<<256, 256, 0, stream>>>(qbf, kbf, vbf, Opart, lpart);
    combine_kernel<<<2048, 256, 0, stream>>>(Opart, lpart, qnb);
    sim_kernel<<<32, 256, 0, stream>>>(vnb, qnb, out);
}

// Round 7
// 121.362 us; speedup vs baseline: 1.0491x; 1.0491x over previous
//
#include <hip/hip_runtime.h>
#include <hip/hip_bf16.h>

#define NROW 8192   // B*A = 64*128
#define INC  128
#define OUTC 64
#define BG   16     // key-split factor

// Q is pre-scaled by log2(e)/sqrt(64) at projection time, so attention
// computes p = exp2(q'.k) with a single v_exp_f32 per score.
#define QSCALE 0.18033688011112042f

typedef __bf16 bf16x8 __attribute__((ext_vector_type(8)));
typedef __bf16 bf16x4 __attribute__((ext_vector_type(4)));
typedef short  s16x4  __attribute__((ext_vector_type(4)));
typedef float  f32x4  __attribute__((ext_vector_type(4)));

static __device__ __forceinline__ f32x4 mfma16(bf16x8 a, bf16x8 b, f32x4 c) {
    return __builtin_amdgcn_mfma_f32_16x16x32_bf16(a, b, c, 0, 0, 0);
}
// 16x16x16 bf16 (K=16). C/D of S^T IS the A-operand layout of P for PV.
static __device__ __forceinline__ f32x4 mfma1k(s16x4 a, s16x4 b, f32x4 c) {
    return __builtin_amdgcn_mfma_f32_16x16x16bf16_1k(a, b, c, 0, 0, 0);
}

static __device__ __forceinline__ bf16x8 cvt8(float4 lo, float4 hi) {
    bf16x8 r;
    r[0] = (__bf16)lo.x; r[1] = (__bf16)lo.y; r[2] = (__bf16)lo.z; r[3] = (__bf16)lo.w;
    r[4] = (__bf16)hi.x; r[5] = (__bf16)hi.y; r[6] = (__bf16)hi.z; r[7] = (__bf16)hi.w;
    return r;
}

// ---------------------------------------------------------------------------
// Kernel 1: projection via MFMA. grid = 256 = b(64) x aq(4), 1 block/CU.
//
// ROUND 7: fused all 3 mats into one block. Previously 768 blocks staged
// every (b,a0) feature slab into LDS 3x (once per mat): 12MB feat reads +
// 3x staging instructions for a 4MB-in/4MB-out op (~15-20us by dispatch
// accounting vs ~4us roofline). Now: slab staged ONCE; the 12 output
// n-tiles (3 mats x 4) are spread 3-per-wave; slab fragments loaded once
// per kc and reused across the wave's 3 tiles. V tiles (8-11) land in vbuf
// as before; block-wide normalize phase unchanged.
__global__ __launch_bounds__(256) void proj_kernel(
    const float* __restrict__ feat,
    const float* __restrict__ Wq, const float* __restrict__ bq,
    const float* __restrict__ Wk, const float* __restrict__ bk,
    const float* __restrict__ Wv, const float* __restrict__ bv,
    __hip_bfloat16* __restrict__ qbf, __hip_bfloat16* __restrict__ kbf,
    __hip_bfloat16* __restrict__ vbf, __hip_bfloat16* __restrict__ vnb)
{
    __shared__ float slab[32 * 132];
    __shared__ float vbuf[32 * 66];
    __shared__ float invb[32];

    const int blk = blockIdx.x;
    const int b   = blk >> 2;
    const int a0  = (blk & 3) * 32;
    const int r0  = b * 128 + a0;
    const float* fb = feat + (size_t)b * INC * 128;

    for (int i = threadIdx.x; i < 32 * 128; i += 256) {
        int c = i >> 5, a = i & 31;
        slab[a * 132 + c] = fb[c * 128 + a0 + a];
    }
    __syncthreads();

    const int w    = threadIdx.x >> 6;
    const int lane = threadIdx.x & 63;
    const int l16  = lane & 15;
    const int quad = lane >> 4;

    // wave w owns n-tiles {3w, 3w+1, 3w+2} of the 12 concatenated Q/K/V tiles
    f32x4 acc[3][2];
    #pragma unroll
    for (int t = 0; t < 3; ++t)
        #pragma unroll
        for (int u = 0; u < 2; ++u)
            acc[t][u] = (f32x4){0.f, 0.f, 0.f, 0.f};

    #pragma unroll
    for (int kc = 0; kc < 4; ++kc) {
        const int k0 = kc * 32 + quad * 8;
        bf16x8 afr[2];
        #pragma unroll
        for (int u = 0; u < 2; ++u) {
            const float* ar = slab + (u * 16 + l16) * 132 + k0;
            afr[u] = cvt8(*(const float4*)ar, *(const float4*)(ar + 4));
        }
        #pragma unroll
        for (int t = 0; t < 3; ++t) {
            const int tile = w * 3 + t;
            const int mat  = tile >> 2;
            const float* W = (mat == 0) ? Wq : (mat == 1) ? Wk : Wv;
            const float* wr = W + ((tile & 3) * 16 + l16) * INC + k0;
            bf16x8 bfr = cvt8(*(const float4*)wr, *(const float4*)(wr + 4));
            #pragma unroll
            for (int u = 0; u < 2; ++u)
                acc[t][u] = mfma16(afr[u], bfr, acc[t][u]);
        }
    }

    #pragma unroll
    for (int t = 0; t < 3; ++t) {
        const int tile = w * 3 + t;
        const int mat  = tile >> 2;
        const int nt   = tile & 3;
        const float* bias = (mat == 0) ? bq : (mat == 1) ? bk : bv;
        const float bl = bias[nt * 16 + l16];
        if (mat < 2) {
            const float sc = (mat == 0) ? QSCALE : 1.0f;
            __hip_bfloat16* dst = mat ? kbf : qbf;
            #pragma unroll
            for (int u = 0; u < 2; ++u) {
                const int base = ((((r0 >> 4) + u) * 4 + nt) << 8) + l16;
                #pragma unroll
                for (int r = 0; r < 4; ++r)
                    dst[base + (quad * 4 + r) * 16] = __float2bfloat16((acc[t][u][r] + bl) * sc);
            }
        } else {
            #pragma unroll
            for (int u = 0; u < 2; ++u)
                #pragma unroll
                for (int r = 0; r < 4; ++r)
                    vbuf[(u * 16 + quad * 4 + r) * 66 + nt * 16 + l16] = acc[t][u][r] + bl;
        }
    }
    __syncthreads();

    // ---- V normalize phase (block-wide, unchanged) ----
    const int rl = threadIdx.x >> 3;
    const int jj = threadIdx.x & 7;
    float ss = 0.f;
    #pragma unroll
    for (int i = 0; i < 8; ++i) {
        float x = vbuf[rl * 66 + jj * 8 + i];
        ss += x * x;
    }
    ss += __shfl_xor(ss, 1, 64);
    ss += __shfl_xor(ss, 2, 64);
    ss += __shfl_xor(ss, 4, 64);
    if (jj == 0) invb[rl] = rsqrtf(fmaxf(ss, 1e-24f));
    __syncthreads();
    float inv = invb[rl];
    bf16x8 vp;
    #pragma unroll
    for (int i = 0; i < 8; ++i)
        vp[i] = (__bf16)(vbuf[rl * 66 + jj * 8 + i] * inv);
    *(bf16x8*)(vnb + (size_t)(r0 + rl) * 64 + jj * 8) = vp;
    const int tl = threadIdx.x & 15;
    const int n  = (threadIdx.x >> 4) & 3;
    const int s_ = threadIdx.x >> 6;
    bf16x8 pack;
    #pragma unroll
    for (int j = 0; j < 8; ++j) {
        int key = s_ * 8 + j;
        pack[j] = (__bf16)(vbuf[key * 66 + n * 16 + tl] * invb[key]);
    }
    const int base = ((((r0 >> 4) + (s_ >> 1)) * 4 + n) << 8) + tl * 16 + (s_ & 1) * 8;
    *(bf16x8*)(vbf + base) = pack;
}

// ---------------------------------------------------------------------------
// Kernel 2: attention. grid = 512 = qb(32) x bg(16); block = 256 q-rows x
// 512 keys; 2 blocks/CU = 2 waves/SIMD (confirmed optimum: r5 -> r6 showed
// 1 wave/SIMD regresses ~8us; r4 -> r5 showed halving per-CU VMEM instrs
// saves ~10-15us). 64 q-rows per wave, K and V double-buffered, streaming
// partial stores (no atomics).
#define ATTN_ITER(K00,K01,K10,K11, NK00,NK01,NK10,NK11,                      \
                  V0,V1,V2,V3,V4,V5,V6,V7,                                   \
                  NV0,NV1,NV2,NV3,NV4,NV5,NV6,NV7)                           \
    do {                                                                     \
        NV0 = *(const s16x4*)(vp);                                           \
        NV1 = *(const s16x4*)(vp + 512);                                     \
        NV2 = *(const s16x4*)(vp + 1024);                                    \
        NV3 = *(const s16x4*)(vp + 1536);                                    \
        NV4 = *(const s16x4*)(vp + 2048);                                    \
        NV5 = *(const s16x4*)(vp + 2560);                                    \
        NV6 = *(const s16x4*)(vp + 3072);                                    \
        NV7 = *(const s16x4*)(vp + 3584);                                    \
        NK00 = *(const bf16x8*)(kp);                                         \
        NK01 = *(const bf16x8*)(kp + 1024);                                  \
        NK10 = *(const bf16x8*)(kp + 2048);                                  \
        NK11 = *(const bf16x8*)(kp + 3072);                                  \
        vp += 4096; kp += 4096;                                              \
        const f32x4 zero = (f32x4){0.f, 0.f, 0.f, 0.f};                      \
        _Pragma("unroll")                                                    \
        for (int u = 0; u < 4; ++u) {                                        \
            f32x4 s0 = mfma16(K00, qf32[u][0], zero);                        \
            s0       = mfma16(K01, qf32[u][1], s0);                          \
            f32x4 s1 = mfma16(K10, qf32[u][0], zero);                        \
            s1       = mfma16(K11, qf32[u][1], s1);                          \
            union { bf16x4 v; s16x4 s; } pf0, pf1;                           \
            _Pragma("unroll")                                                \
            for (int r = 0; r < 4; ++r) {                                    \
                float p0 = __builtin_amdgcn_exp2f(s0[r]);                    \
                float p1 = __builtin_amdgcn_exp2f(s1[r]);                    \
                lp[u] += p0 + p1;                                            \
                pf0.v[r] = (__bf16)p0;                                       \
                pf1.v[r] = (__bf16)p1;                                       \
            }                                                                \
            of[u][0] = mfma1k(pf0.s, V0, of[u][0]);                          \
            of[u][0] = mfma1k(pf1.s, V4, of[u][0]);                          \
            of[u][1] = mfma1k(pf0.s, V1, of[u][1]);                          \
            of[u][1] = mfma1k(pf1.s, V5, of[u][1]);                          \
            of[u][2] = mfma1k(pf0.s, V2, of[u][2]);                          \
            of[u][2] = mfma1k(pf1.s, V6, of[u][2]);                          \
            of[u][3] = mfma1k(pf0.s, V3, of[u][3]);                          \
            of[u][3] = mfma1k(pf1.s, V7, of[u][3]);                          \
        }                                                                    \
    } while (0)

__global__ __launch_bounds__(256, 2) void attn_kernel(
    const __hip_bfloat16* __restrict__ qbf,
    const __hip_bfloat16* __restrict__ kbf,
    const __hip_bfloat16* __restrict__ vbf,
    float* __restrict__ Opart, float* __restrict__ lpart)
{
    const int qb    = blockIdx.x >> 4;
    const int bg    = blockIdx.x & 15;
    const int w     = threadIdx.x >> 6;
    const int lane  = threadIdx.x & 63;
    const int l16   = lane & 15;
    const int quad  = lane >> 4;
    const int r0    = qb * 256 + w * 64;              // 64 q-rows per wave
    const int fo    = l16 * 16 + quad * 4;            // K=16 frag elem offset
    const int fo32  = l16 * 16 + (quad & 1) * 8;      // K=32 frag elem offset
    const int qh    = quad >> 1;                      // K=32 tile-pair half

    // Q fragments in K=32 form: 4 x 16-row subtiles
    bf16x8 qf32[4][2];
    #pragma unroll
    for (int u = 0; u < 4; ++u)
        #pragma unroll
        for (int p = 0; p < 2; ++p)
            qf32[u][p] = *(const bf16x8*)(qbf +
                ((((r0 >> 4) + u) * 4 + p * 2 + qh) << 8) + fo32);

    f32x4 of[4][4];
    float lp[4] = {0.f, 0.f, 0.f, 0.f};
    #pragma unroll
    for (int u = 0; u < 4; ++u)
        #pragma unroll
        for (int n = 0; n < 4; ++n)
            of[u][n] = (f32x4){0.f, 0.f, 0.f, 0.f};

    // byte pointers: chunk stride 2048 B, iteration (2 chunks) stride 4096 B
    const int ck0 = bg * 32;                          // 32 chunks = 512 keys
    const char* kp = (const char*)kbf + ck0 * 2048 + qh * 512 + fo32 * 2;
    const char* vp = (const char*)vbf + ck0 * 2048 + fo * 2;

    bf16x8 kA00, kA01, kA10, kA11, kB00, kB01, kB10, kB11;
    s16x4  vA0, vA1, vA2, vA3, vA4, vA5, vA6, vA7;
    s16x4  vB0, vB1, vB2, vB3, vB4, vB5, vB6, vB7;

    // prologue: load iteration 0's K and V
    vA0 = *(const s16x4*)(vp);
    vA1 = *(const s16x4*)(vp + 512);
    vA2 = *(const s16x4*)(vp + 1024);
    vA3 = *(const s16x4*)(vp + 1536);
    vA4 = *(const s16x4*)(vp + 2048);
    vA5 = *(const s16x4*)(vp + 2560);
    vA6 = *(const s16x4*)(vp + 3072);
    vA7 = *(const s16x4*)(vp + 3584);
    kA00 = *(const bf16x8*)(kp);
    kA01 = *(const bf16x8*)(kp + 1024);
    kA10 = *(const bf16x8*)(kp + 2048);
    kA11 = *(const bf16x8*)(kp + 3072);
    vp += 4096; kp += 4096;

    #pragma unroll 1
    for (int body = 0; body < 8; ++body) {
        ATTN_ITER(kA00, kA01, kA10, kA11, kB00, kB01, kB10, kB11,
                  vA0, vA1, vA2, vA3, vA4, vA5, vA6, vA7,
                  vB0, vB1, vB2, vB3, vB4, vB5, vB6, vB7);
        ATTN_ITER(kB00, kB01, kB10, kB11, kA00, kA01, kA10, kA11,
                  vB0, vB1, vB2, vB3, vB4, vB5, vB6, vB7,
                  vA0, vA1, vA2, vA3, vA4, vA5, vA6, vA7);
    }

    // per-wave l reduction across quads
    #pragma unroll
    for (int u = 0; u < 4; ++u) {
        float v = lp[u];
        v += __shfl_xor(v, 16, 64);
        v += __shfl_xor(v, 32, 64);
        lp[u] = v;
    }

    // streaming per-wave partial: tile = qb*4 + w owns rows [r0, r0+64)
    const int task = (qb * 4 + w) * 16 + bg;
    float* Ob = Opart + (size_t)task * 4096;
    #pragma unroll
    for (int u = 0; u < 4; ++u)
        #pragma unroll
        for (int n = 0; n < 4; ++n)
            #pragma unroll
            for (int r = 0; r < 4; ++r)
                Ob[(u * 16 + quad * 4 + r) * 64 + n * 16 + l16] = of[u][n][r];
    if (quad == 0) {
        #pragma unroll
        for (int u = 0; u < 4; ++u)
            lpart[task * 64 + u * 16 + l16] = lp[u];
    }
}

// ---------------------------------------------------------------------------
// Kernel 3: combine 16 partials/tile (64-row tiles), divide by l,
// l2-normalize -> qnb (bf16). grid = 2048 x 256 (full device).
__global__ __launch_bounds__(256) void combine_kernel(
    const float* __restrict__ Opart, const float* __restrict__ lpart,
    __hip_bfloat16* __restrict__ qnb)
{
    const int r    = blockIdx.x * 4 + (threadIdx.x >> 6);
    const int c    = threadIdx.x & 63;
    const int tile = r >> 6, row = r & 63;
    float acc = 0.f, lsum = 0.f;
    #pragma unroll
    for (int g = 0; g < 16; ++g) {
        int task = tile * 16 + g;
        acc  += Opart[(size_t)task * 4096 + row * 64 + c];
        lsum += lpart[task * 64 + row];
    }
    float q = acc / lsum;
    float ss = q * q;
    ss += __shfl_xor(ss, 1, 64);
    ss += __shfl_xor(ss, 2, 64);
    ss += __shfl_xor(ss, 4, 64);
    ss += __shfl_xor(ss, 8, 64);
    ss += __shfl_xor(ss, 16, 64);
    ss += __shfl_xor(ss, 32, 64);
    qnb[(size_t)r * 64 + c] = __float2bfloat16(q * rsqrtf(fmaxf(ss, 1e-24f)));
}

// ---------------------------------------------------------------------------
// Kernel 4: sim = (1/128) * Vn(64x8192) @ Qn(64x8192)^T, split-K MFMA GEMM.
// 256-thread blocks: 4 waves each take 2 of the 8 k-slices of this block's
// 256-key range; atomicAdd partials (4K distinct addresses).
__global__ __launch_bounds__(256) void sim_kernel(
    const __hip_bfloat16* __restrict__ vnb,
    const __hip_bfloat16* __restrict__ qnb,
    float* __restrict__ out)
{
    const int w    = threadIdx.x >> 6;
    const int lane = threadIdx.x & 63;
    const int l16  = lane & 15;
    const int quad = lane >> 4;
    const int kblk = blockIdx.x * 256;

    f32x4 acc[4][4];
    #pragma unroll
    for (int mi = 0; mi < 4; ++mi)
        #pragma unroll
        for (int ni = 0; ni < 4; ++ni)
            acc[mi][ni] = (f32x4){0.f, 0.f, 0.f, 0.f};

    #pragma unroll
    for (int s = 0; s < 2; ++s) {
        const int ks = w * 2 + s;
        const int k0 = kblk + ks * 32 + quad * 8;
        bf16x8 af[4], bfv[4];
        #pragma unroll
        for (int mi = 0; mi < 4; ++mi)
            af[mi] = *(const bf16x8*)(vnb + (size_t)(mi * 16 + l16) * 8192 + k0);
        #pragma unroll
        for (int ni = 0; ni < 4; ++ni)
            bfv[ni] = *(const bf16x8*)(qnb + (size_t)(ni * 16 + l16) * 8192 + k0);
        #pragma unroll
        for (int mi = 0; mi < 4; ++mi)
            #pragma unroll
            for (int ni = 0; ni < 4; ++ni)
                acc[mi][ni] = mfma16(af[mi], bfv[ni], acc[mi][ni]);
    }

    #pragma unroll
    for (int mi = 0; mi < 4; ++mi)
        #pragma unroll
        for (int ni = 0; ni < 4; ++ni)
            #pragma unroll
            for (int r = 0; r < 4; ++r)
                atomicAdd(&out[(mi * 16 + quad * 4 + r) * 64 + ni * 16 + l16],
                          acc[mi][ni][r] * (1.f / 128.f));
}

// ---------------------------------------------------------------------------
extern "C" void kernel_launch(void* const* d_in, const int* in_sizes, int n_in,
                              void* d_out, int out_size, void* d_ws, size_t ws_size,
                              hipStream_t stream)
{
    const float* feat = (const float*)d_in[0];
    const float* Wq   = (const float*)d_in[1];
    const float* bq   = (const float*)d_in[2];
    const float* Wk   = (const float*)d_in[3];
    const float* bk   = (const float*)d_in[4];
    const float* Wv   = (const float*)d_in[5];
    const float* bv   = (const float*)d_in[6];
    float* out = (float*)d_out;

    const size_t MB = 1u << 20;
    char* ws = (char*)d_ws;
    __hip_bfloat16* qbf = (__hip_bfloat16*)(ws);              // 1 MB (frag-tiled, pre-scaled)
    __hip_bfloat16* kbf = (__hip_bfloat16*)(ws + 1 * MB);     // 1 MB (frag-tiled)
    __hip_bfloat16* vbf = (__hip_bfloat16*)(ws + 2 * MB);     // 1 MB (frag-tiled)
    __hip_bfloat16* vnb = (__hip_bfloat16*)(ws + 3 * MB);     // 1 MB (row-major)
    float* Opart = (float*)(ws + 4 * MB);                     // 32 MB (2048 x 16 KB)
    float* lpart = (float*)(ws + 36 * MB);                    // 512 KB
    __hip_bfloat16* qnb = (__hip_bfloat16*)(ws + 37 * MB);    // 1 MB

    (void)hipMemsetAsync(out, 0, 64 * 64 * sizeof(float), stream);
    proj_kernel<<<256, 256, 0, stream>>>(feat, Wq, bq, Wk, bk, Wv, bv, qbf, kbf, vbf, vnb);
    attn_kernel<<<512, 256, 0, stream>>>(qbf, kbf, vbf, Opart, lpart);
    combine_kernel<<<2048, 256, 0, stream>>>(Opart, lpart, qnb);
    sim_kernel<<<32, 256, 0, stream>>>(vnb, qnb, out);
}